// Round 19
// baseline (380.389 us; speedup 1.0000x reference)
//
#include <hip/hip_runtime.h>

// ---------------- common types/helpers ----------------
typedef float fx4 __attribute__((ext_vector_type(4)));
typedef short s16x4 __attribute__((ext_vector_type(4)));
typedef short s16x8 __attribute__((ext_vector_type(8)));
typedef __bf16 bf16x8 __attribute__((ext_vector_type(8)));

__device__ __forceinline__ short f2bf(float f) {
  unsigned u = __builtin_bit_cast(unsigned, f);
  u += 0x7fffu + ((u >> 16) & 1u);   // RNE
  return (short)(u >> 16);
}
__device__ __forceinline__ float b2f(short s) {
  unsigned u = ((unsigned)(unsigned short)s) << 16;
  return __builtin_bit_cast(float, u);
}

__device__ __forceinline__ bf16x8 ld8(const short* p) {
  s16x8 v = *(const s16x8*)p;
  return __builtin_bit_cast(bf16x8, v);
}

// async global->LDS, 16B per lane; LDS dest is wave-uniform base + lane*16
__device__ __forceinline__ void gld16(const void* g, void* l) {
  __builtin_amdgcn_global_load_lds(
      (const __attribute__((address_space(1))) unsigned*)g,
      (__attribute__((address_space(3))) unsigned*)l, 16, 0, 0);
}

template<int N> __device__ __forceinline__ void wait_vmcnt() {
  if constexpr (N == 0)      asm volatile("s_waitcnt vmcnt(0)" ::: "memory");
  else if constexpr (N == 4) asm volatile("s_waitcnt vmcnt(4)" ::: "memory");
  else if constexpr (N == 6) asm volatile("s_waitcnt vmcnt(6)" ::: "memory");
  __builtin_amdgcn_sched_barrier(0);
}

__device__ __forceinline__ void barrier_pin() {
  __builtin_amdgcn_s_barrier();
  __builtin_amdgcn_sched_barrier(0);
}

// ---------------- f32 -> bf16 convert (x pre-conversion) ----------------
__global__ __launch_bounds__(256) void cvt_k(const float* __restrict__ in,
                                             short* __restrict__ out) {
  int i = (blockIdx.x * 256 + threadIdx.x) * 8;
  fx4 a = *(const fx4*)(in + i);
  fx4 b = *(const fx4*)(in + i + 4);
  s16x8 w;
  w[0] = f2bf(a[0]); w[1] = f2bf(a[1]); w[2] = f2bf(a[2]); w[3] = f2bf(a[3]);
  w[4] = f2bf(b[0]); w[5] = f2bf(b[1]); w[6] = f2bf(b[2]); w[7] = f2bf(b[3]);
  *(s16x8*)(out + i) = w;
}

// ---------------- transpose+convert: out[n][k] = bf16(in[k][n]) ----------------
__global__ __launch_bounds__(256) void tr_k(const float* __restrict__ in,
    short* __restrict__ out, int K, int N) {
  __shared__ short T[64][72];
  const int ktiles = K >> 6;
  const int tk0 = (blockIdx.x % ktiles) << 6;
  const int tn0 = (blockIdx.x / ktiles) << 6;
  const int tid = threadIdx.x;
  #pragma unroll
  for (int i = 0; i < 4; ++i) {
    int idx = i * 256 + tid;
    int k = idx >> 4, n4 = (idx & 15) << 2;
    fx4 v = *(const fx4*)(in + (size_t)(tk0 + k) * N + tn0 + n4);
    #pragma unroll
    for (int j = 0; j < 4; ++j) T[n4 + j][k] = f2bf(v[j]);
  }
  __syncthreads();
  #pragma unroll
  for (int i = 0; i < 2; ++i) {
    int idx = i * 256 + tid;
    int n = idx >> 3, k8 = (idx & 7) << 3;
    *(s16x8*)(out + (size_t)(tn0 + n) * K + tk0 + k8) = *(const s16x8*)&T[n][k8];
  }
}

// ---------------- V transpose: vbt[b][kvh][d][t] = vbp[t(b)][kvh][d] -------
__global__ __launch_bounds__(256) void vtr_k(const short* __restrict__ vbp,
                                             short* __restrict__ vbt) {
  __shared__ short T[64][72];   // T[d][t]
  const int tile = blockIdx.x & 31;
  const int tt = tile & 15, dt = tile >> 4;
  const int bk = blockIdx.x >> 5;
  const int b = bk >> 3, kvh = bk & 7;
  const int t0 = tt << 6, d0 = dt << 6;
  const int tid = threadIdx.x;
  #pragma unroll
  for (int i = 0; i < 2; ++i) {
    int idx = i * 256 + tid;
    int r = idx >> 3, c8 = (idx & 7) << 3;
    s16x8 v = *(const s16x8*)(vbp + (size_t)(b * 1024 + t0 + r) * 1024 + kvh * 128 + d0 + c8);
    #pragma unroll
    for (int j = 0; j < 8; ++j) T[c8 + j][r] = v[j];
  }
  __syncthreads();
  #pragma unroll
  for (int i = 0; i < 2; ++i) {
    int idx = i * 256 + tid;
    int r = idx >> 3, c8 = (idx & 7) << 3;
    *(s16x8*)(vbt + ((size_t)(b * 8 + kvh) * 128 + d0 + r) * 1024 + t0 + c8) =
        *(const s16x8*)&T[r][c8];
  }
}

// ---------------- 8-phase GEMM + fused bulk copy -----------------------------
// m201-faithful phase order: each phase's operand ds_reads are issued BEFORE
// the barrier that opens it (they fly under the neighboring MFMA sections);
// after the barrier only stage-issue + lgkm-wait + MFMA remain. Hoist safety
// (stage ledger): Bs[s][1] next written this tile's q3 (2 barriers after its
// readers); As[s][1] next written t+1.q0; Bs[s][0] next written t+1.q1.
// q0-of-tile reads cannot cross the vmcnt gate and stay after it.
template<int BF16OUT>
__global__ __launch_bounds__(512) void gemm8(const short* __restrict__ A,
    const short* __restrict__ Bt, void* __restrict__ Cp, int N, int K,
    const fx4* __restrict__ csrc, fx4* __restrict__ cdst, int gemmBlocks,
    size_t nvec) {
  const int tid = threadIdx.x;
  if ((int)blockIdx.x >= gemmBlocks) {
    size_t stride = (size_t)(gridDim.x - gemmBlocks) * 512;
    for (size_t i = (size_t)((int)blockIdx.x - gemmBlocks) * 512 + tid;
         i < nvec; i += stride)
      cdst[i] = csrc[i];
    return;
  }
  __shared__ short As[2][2][128 * 64];
  __shared__ short Bs[2][2][128 * 64];
  const int tiles_n = N >> 8;
  const int tm = blockIdx.x / tiles_n, tn = blockIdx.x % tiles_n;
  const int lane = tid & 63, wv = tid >> 6;
  const int wm = (wv >> 2) << 6;
  const int wn = (wv & 3) << 5;
  const int r0 = tm << 8, c0 = tn << 8;
  const int lrow = lane & 15, lg = lane >> 4;

  auto stageA = [&](int t, int hh) {
    int k0 = t << 6, s = t & 1;
    #pragma unroll
    for (int i = 0; i < 2; ++i) {
      int c = i * 512 + tid;
      int row = c >> 3, ch = c & 7;
      gld16(A + (size_t)(r0 + hh * 128 + row) * K + k0 + ((ch ^ (row & 7)) << 3),
            &As[s][hh][(i * 512 + wv * 64) * 8]);
    }
  };
  auto stageB = [&](int t, int hh) {
    int k0 = t << 6, s = t & 1;
    #pragma unroll
    for (int i = 0; i < 2; ++i) {
      int c = i * 512 + tid;
      int row = c >> 3, ch = c & 7;
      gld16(Bt + (size_t)(c0 + hh * 128 + row) * K + k0 + ((ch ^ (row & 7)) << 3),
            &Bs[s][hh][(i * 512 + wv * 64) * 8]);
    }
  };

  fx4 acc[2][2][4][2] = {};
  bf16x8 a[4][2], b[2][2];

  auto ldA = [&](int s, int hh) {
    #pragma unroll
    for (int mf = 0; mf < 4; ++mf) {
      int lr = wm + mf * 16 + lrow;
      #pragma unroll
      for (int ks = 0; ks < 2; ++ks)
        a[mf][ks] = ld8(&As[s][hh][lr * 64 + ((((ks << 2) + lg) ^ (lr & 7)) << 3)]);
    }
  };
  auto ldB = [&](int s, int hh) {
    #pragma unroll
    for (int nf = 0; nf < 2; ++nf) {
      int lr = wn + nf * 16 + lrow;
      #pragma unroll
      for (int ks = 0; ks < 2; ++ks)
        b[nf][ks] = ld8(&Bs[s][hh][lr * 64 + ((((ks << 2) + lg) ^ (lr & 7)) << 3)]);
    }
  };

  #define MFMA8(AC) \
    __builtin_amdgcn_s_setprio(1); \
    _Pragma("unroll") \
    for (int ks = 0; ks < 2; ++ks) \
      _Pragma("unroll") \
      for (int mf = 0; mf < 4; ++mf) \
        _Pragma("unroll") \
        for (int nf = 0; nf < 2; ++nf) \
          AC[mf][nf] = __builtin_amdgcn_mfma_f32_16x16x32_bf16( \
              a[mf][ks], b[nf][ks], AC[mf][nf], 0, 0, 0); \
    __builtin_amdgcn_s_setprio(0);

  const int nt = K >> 6;
  stageA(0, 0); stageA(0, 1); stageB(0, 0); stageB(0, 1);
  stageA(1, 0); stageB(1, 1);

  for (int t = 0; t < nt; ++t) {
    const int s = t & 1;
    // ---- q0: gate + in-phase reads (cannot hoist across gate) ----
    if (t + 1 < nt) wait_vmcnt<4>(); else wait_vmcnt<0>();
    barrier_pin();
    ldA(s, 0); ldB(s, 0);
    if (t + 1 < nt) stageA(t + 1, 1);
    MFMA8(acc[0][0]);
    ldB(s, 1);                           // hoist q1's B under q0's tail
    __builtin_amdgcn_sched_barrier(0);
    barrier_pin();
    // ---- q1 ----
    if (t + 1 < nt) stageB(t + 1, 0);
    MFMA8(acc[0][1]);
    ldA(s, 1);                           // hoist q2's A
    __builtin_amdgcn_sched_barrier(0);
    barrier_pin();
    // ---- q2 ----
    if (t + 2 < nt) stageA(t + 2, 0);
    MFMA8(acc[1][1]);
    ldB(s, 0);                           // hoist q3's B
    __builtin_amdgcn_sched_barrier(0);
    barrier_pin();
    // ---- q3 ----
    if (t + 2 < nt) stageB(t + 2, 1);
    MFMA8(acc[1][0]);
    barrier_pin();
  }
  #undef MFMA8
  const int g4 = lg << 2;
  #pragma unroll
  for (int mq = 0; mq < 2; ++mq)
    #pragma unroll
    for (int nq = 0; nq < 2; ++nq)
      #pragma unroll
      for (int mf = 0; mf < 4; ++mf)
        #pragma unroll
        for (int nf = 0; nf < 2; ++nf)
          #pragma unroll
          for (int j = 0; j < 4; ++j) {
            int row = r0 + mq * 128 + wm + mf * 16 + g4 + j;
            int col = c0 + nq * 128 + wn + nf * 16 + lrow;
            if (BF16OUT)
              ((short*)Cp)[(size_t)row * N + col] = f2bf(acc[mq][nq][mf][nf][j]);
            else
              ((float*)Cp)[(size_t)row * N + col] = acc[mq][nq][mf][nf][j];
          }
}

// ---------------- 4-phase GEMM: BM=256, BN=128, BK=64 (O-proj) ---------------
// Same hoist: p1's A ds_reads issued before the p0->p1 barrier. As[s][1]
// (3-slot ring) is next written during tile t+1 -> safe.
__global__ __launch_bounds__(512) void gemm4(const short* __restrict__ A,
    const short* __restrict__ Bt, float* __restrict__ Cp, int N, int K) {
  __shared__ short As[3][2][128 * 64];
  __shared__ short Bs[3][128 * 64];
  const int tiles_n = N >> 7;
  const int tm = blockIdx.x / tiles_n, tn = blockIdx.x % tiles_n;
  const int tid = threadIdx.x;
  const int lane = tid & 63, wv = tid >> 6;
  const int wm = (wv >> 2) << 6;
  const int wn = (wv & 3) << 5;
  const int r0 = tm << 8, c0 = tn << 7;
  const int lrow = lane & 15, lg = lane >> 4;

  auto stageA = [&](int t, int hh) {
    int k0 = t << 6, s = t % 3;
    #pragma unroll
    for (int i = 0; i < 2; ++i) {
      int c = i * 512 + tid;
      int row = c >> 3, ch = c & 7;
      gld16(A + (size_t)(r0 + hh * 128 + row) * K + k0 + ((ch ^ (row & 7)) << 3),
            &As[s][hh][(i * 512 + wv * 64) * 8]);
    }
  };
  auto stageB = [&](int t) {
    int k0 = t << 6, s = t % 3;
    #pragma unroll
    for (int i = 0; i < 2; ++i) {
      int c = i * 512 + tid;
      int row = c >> 3, ch = c & 7;
      gld16(Bt + (size_t)(c0 + row) * K + k0 + ((ch ^ (row & 7)) << 3),
            &Bs[s][(i * 512 + wv * 64) * 8]);
    }
  };

  fx4 acc[2][4][2] = {};
  bf16x8 a[4][2], b[2][2];

  auto ldA = [&](int s, int hh) {
    #pragma unroll
    for (int mf = 0; mf < 4; ++mf) {
      int lr = wm + mf * 16 + lrow;
      #pragma unroll
      for (int ks = 0; ks < 2; ++ks)
        a[mf][ks] = ld8(&As[s][hh][lr * 64 + ((((ks << 2) + lg) ^ (lr & 7)) << 3)]);
    }
  };
  auto ldB = [&](int s) {
    #pragma unroll
    for (int nf = 0; nf < 2; ++nf) {
      int lr = wn + nf * 16 + lrow;
      #pragma unroll
      for (int ks = 0; ks < 2; ++ks)
        b[nf][ks] = ld8(&Bs[s][lr * 64 + ((((ks << 2) + lg) ^ (lr & 7)) << 3)]);
    }
  };

  #define MFMA4(AC) \
    __builtin_amdgcn_s_setprio(1); \
    _Pragma("unroll") \
    for (int ks = 0; ks < 2; ++ks) \
      _Pragma("unroll") \
      for (int mf = 0; mf < 4; ++mf) \
        _Pragma("unroll") \
        for (int nf = 0; nf < 2; ++nf) \
          AC[mf][nf] = __builtin_amdgcn_mfma_f32_16x16x32_bf16( \
              a[mf][ks], b[nf][ks], AC[mf][nf], 0, 0, 0); \
    __builtin_amdgcn_s_setprio(0);

  const int nt = K >> 6;
  stageA(0, 0); stageA(0, 1); stageB(0);
  stageA(1, 0); stageA(1, 1); stageB(1);

  for (int t = 0; t < nt; ++t) {
    const int s = t % 3;
    if (t + 1 < nt) wait_vmcnt<6>(); else wait_vmcnt<0>();
    barrier_pin();
    ldA(s, 0); ldB(s);
    if (t + 2 < nt) stageA(t + 2, 0);
    MFMA4(acc[0]);
    ldA(s, 1);                           // hoist p1's A under p0's tail
    __builtin_amdgcn_sched_barrier(0);
    barrier_pin();
    if (t + 2 < nt) { stageA(t + 2, 1); stageB(t + 2); }
    MFMA4(acc[1]);
    barrier_pin();
  }
  #undef MFMA4
  const int g4 = lg << 2;
  #pragma unroll
  for (int mh = 0; mh < 2; ++mh)
    #pragma unroll
    for (int mf = 0; mf < 4; ++mf)
      #pragma unroll
      for (int nf = 0; nf < 2; ++nf)
        #pragma unroll
        for (int j = 0; j < 4; ++j) {
          int row = r0 + mh * 128 + wm + mf * 16 + g4 + j;
          int col = c0 + wn + nf * 16 + lrow;
          Cp[(size_t)row * N + col] = acc[mh][mf][nf][j];
        }
}

// ---------------- RMSNorm + RoPE + KV scatter (bf16 xqkv input) --------------
__global__ __launch_bounds__(256) void nr_k(const short* __restrict__ xqkv,
    const float* __restrict__ qnw, const float* __restrict__ knw,
    const float* __restrict__ cosb, const float* __restrict__ sinb,
    const int* __restrict__ idx,
    short* __restrict__ qb, short* __restrict__ kbp, short* __restrict__ vbp,
    float* __restrict__ bufo) {
  int rid = blockIdx.x * 4 + (threadIdx.x >> 6);
  int l = threadIdx.x & 63;
  int type, t, h;
  if (rid < 65536)      { type = 0; t = rid >> 5; h = rid & 31; }
  else if (rid < 81920) { type = 1; int r = rid - 65536; t = r >> 3; h = r & 7; }
  else                  { type = 2; int r = rid - 81920; t = r >> 3; h = r & 7; }
  int s = t & 1023;
  const short* src = xqkv + (size_t)t * 6144 +
                     ((type == 0) ? h * 128 : (type == 1) ? 4096 + h * 128
                                                          : 5120 + h * 128);
  float e0 = b2f(src[l]), e1 = b2f(src[l + 64]);
  float out0, out1;
  if (type < 2) {
    float ss = e0 * e0 + e1 * e1;
    #pragma unroll
    for (int off = 1; off < 64; off <<= 1) ss += __shfl_xor(ss, off);
    float r = rsqrtf(ss * (1.0f / 128.0f) + 1e-6f);
    const float* nw = (type == 0) ? qnw : knw;
    float n0 = e0 * r * nw[l], n1 = e1 * r * nw[l + 64];
    float c0 = cosb[s * 128 + l], c1 = cosb[s * 128 + 64 + l];
    float s0 = sinb[s * 128 + l], s1 = sinb[s * 128 + 64 + l];
    out0 = n0 * c0 - n1 * s0;
    out1 = n1 * c1 + n0 * s1;
  } else { out0 = e0; out1 = e1; }
  if (type == 0) {
    short* d = qb + (size_t)t * 4096 + h * 128;
    d[l] = f2bf(out0); d[l + 64] = f2bf(out1);
  } else {
    int br = idx[t];
    float* bd = bufo + (size_t)br * 2048 + (type == 1 ? 0 : 1024) + h * 128;
    bd[l] = out0; bd[l + 64] = out1;
    short* d = (type == 1) ? kbp + (size_t)t * 1024 + h * 128
                           : vbp + (size_t)t * 1024 + h * 128;
    d[l] = f2bf(out0); d[l + 64] = f2bf(out1);
  }
}

// ---------------- causal GQA flash attention (8-wave, 128 q-rows/block) ------
#define KLD 136
#define PLD 72

__global__ __launch_bounds__(512) void attn_k(const short* __restrict__ qb,
    const short* __restrict__ kbp, const short* __restrict__ vbt,
    short* __restrict__ ob) {
  __shared__ short Ks[64 * KLD];
  __shared__ short Vs[128 * 64];
  __shared__ short Ps[8][16 * PLD];
  const int bid = blockIdx.x;
  const int p = 7 - (bid & 7), h = (bid >> 3) & 31, b = bid >> 8;
  const int kvh = h >> 2;
  const int tid = threadIdx.x, lane = tid & 63, w = tid >> 6;   // w 0..7
  const int lrow = lane & 15, lg = lane >> 4, lk = lg << 3;
  const int q0 = p << 7;
  const int ktmax = 2 * p + 1;
  const float SC2 = 0.088388347648318447f * 1.4426950408889634f; // scale*log2(e)

  bf16x8 qf[4];
  {
    const short* qp = qb + ((size_t)(b * 1024 + q0 + w * 16 + lrow) * 32 + h) * 128 + lk;
    #pragma unroll
    for (int kb4 = 0; kb4 < 4; ++kb4) qf[kb4] = ld8(qp + kb4 * 32);
  }

  const short* vt_base = vbt + (size_t)(b * 8 + kvh) * 128 * 1024;

  const int sd8 = (tid & 15) << 3;
  s16x8 kreg[2], vreg[2];
  auto ldkv = [&](int kv0) {
    #pragma unroll
    for (int it = 0; it < 2; ++it) {
      int r = (it << 5) + (tid >> 4);            // 0..63
      kreg[it] = *(const s16x8*)(kbp + ((size_t)(b * 1024 + kv0 + r) * 8 + kvh) * 128 + sd8);
      int d = (it << 6) + (tid >> 3);            // 0..127
      vreg[it] = *(const s16x8*)(vt_base + (size_t)d * 1024 + kv0 + ((tid & 7) << 3));
    }
  };
  auto wrkv = [&]() {
    #pragma unroll
    for (int it = 0; it < 2; ++it) {
      int r = (it << 5) + (tid >> 4);
      *(s16x8*)&Ks[r * KLD + sd8] = kreg[it];
      int d = (it << 6) + (tid >> 3);
      *(s16x8*)&Vs[d * 64 + (((tid & 7) ^ (d & 7)) << 3)] = vreg[it];
    }
  };

  float m[4], lsum[4];
  fx4 acc[8] = {};
  #pragma unroll
  for (int j = 0; j < 4; ++j) { m[j] = -3.0e38f; lsum[j] = 0.f; }

  ldkv(0);
  wrkv();
  __syncthreads();

  for (int kt = 0; kt <= ktmax; ++kt) {
    const int kv0 = kt << 6;
    if (kt < ktmax) ldkv((kt + 1) << 6);   // T14: issue next tile's loads early
    fx4 sf[4];
    #pragma unroll
    for (int nc = 0; nc < 4; ++nc) {
      fx4 z = {0.f, 0.f, 0.f, 0.f};
      sf[nc] = z;
      #pragma unroll
      for (int kb4 = 0; kb4 < 4; ++kb4) {
        bf16x8 kf = ld8(&Ks[(nc * 16 + lrow) * KLD + kb4 * 32 + lk]);
        sf[nc] = __builtin_amdgcn_mfma_f32_16x16x32_bf16(qf[kb4], kf, sf[nc], 0, 0, 0);
      }
    }
    if (kt >= ktmax - 1) {   // last two tiles straddle the causal diagonal
      #pragma unroll
      for (int nc = 0; nc < 4; ++nc)
        #pragma unroll
        for (int j = 0; j < 4; ++j) {
          int qr = q0 + w * 16 + (lg << 2) + j;
          int kc = kv0 + nc * 16 + lrow;
          if (kc > qr) sf[nc][j] = -3.0e38f;
        }
    }
    float pm[4];
    #pragma unroll
    for (int j = 0; j < 4; ++j) pm[j] = -3.0e38f;
    #pragma unroll
    for (int nc = 0; nc < 4; ++nc)
      #pragma unroll
      for (int j = 0; j < 4; ++j) pm[j] = fmaxf(pm[j], sf[nc][j]);
    #pragma unroll
    for (int j = 0; j < 4; ++j) {
      pm[j] = fmaxf(pm[j], __shfl_xor(pm[j], 1));
      pm[j] = fmaxf(pm[j], __shfl_xor(pm[j], 2));
      pm[j] = fmaxf(pm[j], __shfl_xor(pm[j], 4));
      pm[j] = fmaxf(pm[j], __shfl_xor(pm[j], 8));
    }
    float alpha[4], rs[4];
    #pragma unroll
    for (int j = 0; j < 4; ++j) {
      float mn = fmaxf(m[j], pm[j]);
      alpha[j] = exp2f((m[j] - mn) * SC2);
      m[j] = mn;
      rs[j] = 0.f;
    }
    #pragma unroll
    for (int nc = 0; nc < 4; ++nc)
      #pragma unroll
      for (int j = 0; j < 4; ++j) {
        float pv = exp2f((sf[nc][j] - m[j]) * SC2);
        rs[j] += pv;
        Ps[w][((lg << 2) + j) * PLD + nc * 16 + lrow] = f2bf(pv);
      }
    #pragma unroll
    for (int j = 0; j < 4; ++j) {
      rs[j] += __shfl_xor(rs[j], 1);
      rs[j] += __shfl_xor(rs[j], 2);
      rs[j] += __shfl_xor(rs[j], 4);
      rs[j] += __shfl_xor(rs[j], 8);
      lsum[j] = lsum[j] * alpha[j] + rs[j];
    }
    #pragma unroll
    for (int dg = 0; dg < 8; ++dg)
      #pragma unroll
      for (int j = 0; j < 4; ++j) acc[dg][j] *= alpha[j];
    #pragma unroll
    for (int kb2 = 0; kb2 < 2; ++kb2) {
      bf16x8 pf = ld8(&Ps[w][lrow * PLD + kb2 * 32 + lk]);
      #pragma unroll
      for (int dg = 0; dg < 8; ++dg) {
        int d = dg * 16 + lrow;
        int tch = (kb2 << 2) + lg;
        bf16x8 vf = ld8(&Vs[d * 64 + ((tch ^ (d & 7)) << 3)]);
        acc[dg] = __builtin_amdgcn_mfma_f32_16x16x32_bf16(pf, vf, acc[dg], 0, 0, 0);
      }
    }
    __syncthreads();
    if (kt < ktmax) {
      wrkv();
      __syncthreads();
    }
  }
  #pragma unroll
  for (int j = 0; j < 4; ++j) {
    float rl = 1.0f / lsum[j];
    int t = b * 1024 + q0 + w * 16 + (lg << 2) + j;
    short* op = ob + ((size_t)t * 32 + h) * 128;
    #pragma unroll
    for (int dg = 0; dg < 8; ++dg)
      op[dg * 16 + lrow] = f2bf(acc[dg][j] * rl);
  }
}

// ---------------- launcher ----------------
extern "C" void kernel_launch(void* const* d_in, const int* in_sizes, int n_in,
                              void* d_out, int out_size, void* d_ws, size_t ws_size,
                              hipStream_t stream) {
  (void)in_sizes; (void)n_in; (void)out_size; (void)ws_size;
  const float* x    = (const float*)d_in[0];
  const float* qw   = (const float*)d_in[1];
  const float* kvw  = (const float*)d_in[2];
  const float* ow   = (const float*)d_in[3];
  const float* qnw  = (const float*)d_in[4];
  const float* knw  = (const float*)d_in[5];
  const float* cosb = (const float*)d_in[6];
  const float* sinb = (const float*)d_in[7];
  const float* kvbf = (const float*)d_in[8];
  const int*   idx  = (const int*)d_in[9];

  float* outp = (float*)d_out;
  float* bufp = outp + (size_t)2048 * 4096;   // 16384 rows x 2048 f32 = 134 MB

  // workspace
  char* ws = (char*)d_ws;
  short* xqkv = (short*)ws;                                   // bf16 [2048][6144], 25 MB
  short* qb   = (short*)(ws + (size_t)2048 * 6144 * 4);       // 16.8 MB (offset keeps slack)
  short* kbp  = (short*)((char*)qb + (size_t)2048 * 4096 * 2); // 4.2 MB
  short* vbp  = (short*)((char*)kbp + (size_t)2048 * 1024 * 2);// 4.2 MB
  short* attnb = (short*)(ws + (size_t)2048 * 6144 * 2);      // after bf16 xqkv, 16.8 MB
  short* owt   = (short*)((char*)qb + (size_t)2048 * 4096 * 2 + (size_t)2048 * 2048 * 2 * 2); // after vbp
  short* vbt   = owt;   // vbt (4.2 MB) lives in owt region DURING attn

  // scratch inside the kv_buffer output region (dead until copied/scattered):
  short* xb    = (short*)bufp;
  short* wqkvt = (short*)(bufp + (size_t)2048 * 2048);

  // 1) pre-convert x to bf16; transpose fused [qw|kvw] -> bf16 [6144][4096]
  cvt_k<<<dim3(4096), dim3(256), 0, stream>>>(x, xb);
  tr_k<<<dim3(64 * 64), dim3(256), 0, stream>>>(qw, wqkvt, 4096, 4096);
  tr_k<<<dim3(64 * 32), dim3(256), 0, stream>>>(kvw, wqkvt + (size_t)4096 * 4096, 4096, 2048);
  // 2) fused QKV projection (8-phase, bf16 out) + bulk kv-buffer copy of rows
  //    8192..16383 on the 64 idle CUs: grid 192 GEMM + 64 copy blocks
  {
    const fx4* csrc = (const fx4*)(kvbf + (size_t)8192 * 2048);
    fx4* cdst = (fx4*)(bufp + (size_t)8192 * 2048);
    size_t nvec = (size_t)8192 * 2048 / 4;   // 4.19M f32x4
    gemm8<1><<<dim3(256), dim3(512), 0, stream>>>(xb, wqkvt, (void*)xqkv, 6144, 4096,
                                                  csrc, cdst, 192, nvec);
  }
  // 3) residual kv buffer copy: rows 2048..8191 (kills wqkvt), then norm/rope/scatter
  hipMemcpyAsync(bufp + (size_t)2048 * 2048, kvbf + (size_t)2048 * 2048,
                 (size_t)6144 * 2048 * 4, hipMemcpyDeviceToDevice, stream);
  nr_k<<<dim3(98304 / 4), dim3(256), 0, stream>>>(xqkv, qnw, knw, cosb, sinb, idx,
                                                  qb, kbp, vbp, bufp);
  // 4) V transpose once (into owt region), then attention (8-wave blocks)
  vtr_k<<<dim3(512), dim3(256), 0, stream>>>(vbp, vbt);
  attn_k<<<dim3(2 * 32 * 8), dim3(512), 0, stream>>>(qb, kbp, vbt, attnb);
  // 5) O-weight transpose (overwrites vbt — attn done), then O-proj (4-phase)
  tr_k<<<dim3(64 * 64), dim3(256), 0, stream>>>(ow, owt, 4096, 4096);
  gemm4<<<dim3(8 * 32), dim3(512), 0, stream>>>(attnb, owt, outp, 4096, 4096);
}

// Round 20
// 359.560 us; speedup vs baseline: 1.0579x; 1.0579x over previous
//
#include <hip/hip_runtime.h>

// ---------------- common types/helpers ----------------
typedef float fx4 __attribute__((ext_vector_type(4)));
typedef short s16x4 __attribute__((ext_vector_type(4)));
typedef short s16x8 __attribute__((ext_vector_type(8)));
typedef __bf16 bf16x8 __attribute__((ext_vector_type(8)));

__device__ __forceinline__ short f2bf(float f) {
  unsigned u = __builtin_bit_cast(unsigned, f);
  u += 0x7fffu + ((u >> 16) & 1u);   // RNE
  return (short)(u >> 16);
}
__device__ __forceinline__ float b2f(short s) {
  unsigned u = ((unsigned)(unsigned short)s) << 16;
  return __builtin_bit_cast(float, u);
}

__device__ __forceinline__ bf16x8 ld8(const short* p) {
  s16x8 v = *(const s16x8*)p;
  return __builtin_bit_cast(bf16x8, v);
}

// async global->LDS, 16B per lane; LDS dest is wave-uniform base + lane*16
__device__ __forceinline__ void gld16(const void* g, void* l) {
  __builtin_amdgcn_global_load_lds(
      (const __attribute__((address_space(1))) unsigned*)g,
      (__attribute__((address_space(3))) unsigned*)l, 16, 0, 0);
}

template<int N> __device__ __forceinline__ void wait_vmcnt() {
  if constexpr (N == 0)      asm volatile("s_waitcnt vmcnt(0)" ::: "memory");
  else if constexpr (N == 4) asm volatile("s_waitcnt vmcnt(4)" ::: "memory");
  else if constexpr (N == 6) asm volatile("s_waitcnt vmcnt(6)" ::: "memory");
  __builtin_amdgcn_sched_barrier(0);
}

__device__ __forceinline__ void barrier_pin() {
  __builtin_amdgcn_s_barrier();
  __builtin_amdgcn_sched_barrier(0);
}

// ---------------- f32 -> bf16 convert (x pre-conversion) ----------------
__global__ __launch_bounds__(256) void cvt_k(const float* __restrict__ in,
                                             short* __restrict__ out) {
  int i = (blockIdx.x * 256 + threadIdx.x) * 8;
  fx4 a = *(const fx4*)(in + i);
  fx4 b = *(const fx4*)(in + i + 4);
  s16x8 w;
  w[0] = f2bf(a[0]); w[1] = f2bf(a[1]); w[2] = f2bf(a[2]); w[3] = f2bf(a[3]);
  w[4] = f2bf(b[0]); w[5] = f2bf(b[1]); w[6] = f2bf(b[2]); w[7] = f2bf(b[3]);
  *(s16x8*)(out + i) = w;
}

// ---------------- transpose+convert: out[n][k] = bf16(in[k][n]) ----------------
__global__ __launch_bounds__(256) void tr_k(const float* __restrict__ in,
    short* __restrict__ out, int K, int N) {
  __shared__ short T[64][72];
  const int ktiles = K >> 6;
  const int tk0 = (blockIdx.x % ktiles) << 6;
  const int tn0 = (blockIdx.x / ktiles) << 6;
  const int tid = threadIdx.x;
  #pragma unroll
  for (int i = 0; i < 4; ++i) {
    int idx = i * 256 + tid;
    int k = idx >> 4, n4 = (idx & 15) << 2;
    fx4 v = *(const fx4*)(in + (size_t)(tk0 + k) * N + tn0 + n4);
    #pragma unroll
    for (int j = 0; j < 4; ++j) T[n4 + j][k] = f2bf(v[j]);
  }
  __syncthreads();
  #pragma unroll
  for (int i = 0; i < 2; ++i) {
    int idx = i * 256 + tid;
    int n = idx >> 3, k8 = (idx & 7) << 3;
    *(s16x8*)(out + (size_t)(tn0 + n) * K + tk0 + k8) = *(const s16x8*)&T[n][k8];
  }
}

// ---------------- V transpose: vbt[b][kvh][d][t] = vbp[t(b)][kvh][d] -------
__global__ __launch_bounds__(256) void vtr_k(const short* __restrict__ vbp,
                                             short* __restrict__ vbt) {
  __shared__ short T[64][72];   // T[d][t]
  const int tile = blockIdx.x & 31;
  const int tt = tile & 15, dt = tile >> 4;
  const int bk = blockIdx.x >> 5;
  const int b = bk >> 3, kvh = bk & 7;
  const int t0 = tt << 6, d0 = dt << 6;
  const int tid = threadIdx.x;
  #pragma unroll
  for (int i = 0; i < 2; ++i) {
    int idx = i * 256 + tid;
    int r = idx >> 3, c8 = (idx & 7) << 3;
    s16x8 v = *(const s16x8*)(vbp + (size_t)(b * 1024 + t0 + r) * 1024 + kvh * 128 + d0 + c8);
    #pragma unroll
    for (int j = 0; j < 8; ++j) T[c8 + j][r] = v[j];
  }
  __syncthreads();
  #pragma unroll
  for (int i = 0; i < 2; ++i) {
    int idx = i * 256 + tid;
    int r = idx >> 3, c8 = (idx & 7) << 3;
    *(s16x8*)(vbt + ((size_t)(b * 8 + kvh) * 128 + d0 + r) * 1024 + t0 + c8) =
        *(const s16x8*)&T[r][c8];
  }
}

// ---------------- 8-phase GEMM (verified r11) + fused bulk copy --------------
// Blocks [0, gemmBlocks): BM=BN=256 8-phase GEMM (unchanged schedule).
// Blocks [gemmBlocks, grid): grid-stride f32x4 copy (fills idle CUs at 75%
// GEMM fill; copy blocks use no barriers -> no interaction with the schedule).
template<int BF16OUT>
__global__ __launch_bounds__(512) void gemm8(const short* __restrict__ A,
    const short* __restrict__ Bt, void* __restrict__ Cp, int N, int K,
    const fx4* __restrict__ csrc, fx4* __restrict__ cdst, int gemmBlocks,
    size_t nvec) {
  const int tid = threadIdx.x;
  if ((int)blockIdx.x >= gemmBlocks) {
    size_t stride = (size_t)(gridDim.x - gemmBlocks) * 512;
    for (size_t i = (size_t)((int)blockIdx.x - gemmBlocks) * 512 + tid;
         i < nvec; i += stride)
      cdst[i] = csrc[i];
    return;
  }
  __shared__ short As[2][2][128 * 64];
  __shared__ short Bs[2][2][128 * 64];
  const int tiles_n = N >> 8;
  const int tm = blockIdx.x / tiles_n, tn = blockIdx.x % tiles_n;
  const int lane = tid & 63, wv = tid >> 6;
  const int wm = (wv >> 2) << 6;
  const int wn = (wv & 3) << 5;
  const int r0 = tm << 8, c0 = tn << 8;
  const int lrow = lane & 15, lg = lane >> 4;

  auto stageA = [&](int t, int hh) {
    int k0 = t << 6, s = t & 1;
    #pragma unroll
    for (int i = 0; i < 2; ++i) {
      int c = i * 512 + tid;
      int row = c >> 3, ch = c & 7;
      gld16(A + (size_t)(r0 + hh * 128 + row) * K + k0 + ((ch ^ (row & 7)) << 3),
            &As[s][hh][(i * 512 + wv * 64) * 8]);
    }
  };
  auto stageB = [&](int t, int hh) {
    int k0 = t << 6, s = t & 1;
    #pragma unroll
    for (int i = 0; i < 2; ++i) {
      int c = i * 512 + tid;
      int row = c >> 3, ch = c & 7;
      gld16(Bt + (size_t)(c0 + hh * 128 + row) * K + k0 + ((ch ^ (row & 7)) << 3),
            &Bs[s][hh][(i * 512 + wv * 64) * 8]);
    }
  };

  fx4 acc[2][2][4][2] = {};
  bf16x8 a[4][2], b[2][2];

  auto ldA = [&](int s, int hh) {
    #pragma unroll
    for (int mf = 0; mf < 4; ++mf) {
      int lr = wm + mf * 16 + lrow;
      #pragma unroll
      for (int ks = 0; ks < 2; ++ks)
        a[mf][ks] = ld8(&As[s][hh][lr * 64 + ((((ks << 2) + lg) ^ (lr & 7)) << 3)]);
    }
  };
  auto ldB = [&](int s, int hh) {
    #pragma unroll
    for (int nf = 0; nf < 2; ++nf) {
      int lr = wn + nf * 16 + lrow;
      #pragma unroll
      for (int ks = 0; ks < 2; ++ks)
        b[nf][ks] = ld8(&Bs[s][hh][lr * 64 + ((((ks << 2) + lg) ^ (lr & 7)) << 3)]);
    }
  };

  const int nt = K >> 6;
  stageA(0, 0); stageA(0, 1); stageB(0, 0); stageB(0, 1);
  stageA(1, 0); stageB(1, 1);

  for (int t = 0; t < nt; ++t) {
    const int s = t & 1;
    if (t + 1 < nt) wait_vmcnt<4>(); else wait_vmcnt<0>();
    barrier_pin();
    ldA(s, 0); ldB(s, 0);
    if (t + 1 < nt) stageA(t + 1, 1);
    __builtin_amdgcn_s_setprio(1);
    #pragma unroll
    for (int ks = 0; ks < 2; ++ks)
      #pragma unroll
      for (int mf = 0; mf < 4; ++mf)
        #pragma unroll
        for (int nf = 0; nf < 2; ++nf)
          acc[0][0][mf][nf] = __builtin_amdgcn_mfma_f32_16x16x32_bf16(
              a[mf][ks], b[nf][ks], acc[0][0][mf][nf], 0, 0, 0);
    __builtin_amdgcn_s_setprio(0);
    barrier_pin();
    ldB(s, 1);
    if (t + 1 < nt) stageB(t + 1, 0);
    __builtin_amdgcn_s_setprio(1);
    #pragma unroll
    for (int ks = 0; ks < 2; ++ks)
      #pragma unroll
      for (int mf = 0; mf < 4; ++mf)
        #pragma unroll
        for (int nf = 0; nf < 2; ++nf)
          acc[0][1][mf][nf] = __builtin_amdgcn_mfma_f32_16x16x32_bf16(
              a[mf][ks], b[nf][ks], acc[0][1][mf][nf], 0, 0, 0);
    __builtin_amdgcn_s_setprio(0);
    barrier_pin();
    ldA(s, 1);
    if (t + 2 < nt) stageA(t + 2, 0);
    __builtin_amdgcn_s_setprio(1);
    #pragma unroll
    for (int ks = 0; ks < 2; ++ks)
      #pragma unroll
      for (int mf = 0; mf < 4; ++mf)
        #pragma unroll
        for (int nf = 0; nf < 2; ++nf)
          acc[1][1][mf][nf] = __builtin_amdgcn_mfma_f32_16x16x32_bf16(
              a[mf][ks], b[nf][ks], acc[1][1][mf][nf], 0, 0, 0);
    __builtin_amdgcn_s_setprio(0);
    barrier_pin();
    ldB(s, 0);
    if (t + 2 < nt) stageB(t + 2, 1);
    __builtin_amdgcn_s_setprio(1);
    #pragma unroll
    for (int ks = 0; ks < 2; ++ks)
      #pragma unroll
      for (int mf = 0; mf < 4; ++mf)
        #pragma unroll
        for (int nf = 0; nf < 2; ++nf)
          acc[1][0][mf][nf] = __builtin_amdgcn_mfma_f32_16x16x32_bf16(
              a[mf][ks], b[nf][ks], acc[1][0][mf][nf], 0, 0, 0);
    __builtin_amdgcn_s_setprio(0);
    barrier_pin();
  }
  const int g4 = lg << 2;
  #pragma unroll
  for (int mq = 0; mq < 2; ++mq)
    #pragma unroll
    for (int nq = 0; nq < 2; ++nq)
      #pragma unroll
      for (int mf = 0; mf < 4; ++mf)
        #pragma unroll
        for (int nf = 0; nf < 2; ++nf)
          #pragma unroll
          for (int j = 0; j < 4; ++j) {
            int row = r0 + mq * 128 + wm + mf * 16 + g4 + j;
            int col = c0 + nq * 128 + wn + nf * 16 + lrow;
            if (BF16OUT)
              ((short*)Cp)[(size_t)row * N + col] = f2bf(acc[mq][nq][mf][nf][j]);
            else
              ((float*)Cp)[(size_t)row * N + col] = acc[mq][nq][mf][nf][j];
          }
}

// ---------------- 4-phase GEMM (r12): BM=256, BN=128, BK=64 (O-proj) ----------
__global__ __launch_bounds__(512) void gemm4(const short* __restrict__ A,
    const short* __restrict__ Bt, float* __restrict__ Cp, int N, int K) {
  __shared__ short As[3][2][128 * 64];
  __shared__ short Bs[3][128 * 64];
  const int tiles_n = N >> 7;
  const int tm = blockIdx.x / tiles_n, tn = blockIdx.x % tiles_n;
  const int tid = threadIdx.x;
  const int lane = tid & 63, wv = tid >> 6;
  const int wm = (wv >> 2) << 6;
  const int wn = (wv & 3) << 5;
  const int r0 = tm << 8, c0 = tn << 7;
  const int lrow = lane & 15, lg = lane >> 4;

  auto stageA = [&](int t, int hh) {
    int k0 = t << 6, s = t % 3;
    #pragma unroll
    for (int i = 0; i < 2; ++i) {
      int c = i * 512 + tid;
      int row = c >> 3, ch = c & 7;
      gld16(A + (size_t)(r0 + hh * 128 + row) * K + k0 + ((ch ^ (row & 7)) << 3),
            &As[s][hh][(i * 512 + wv * 64) * 8]);
    }
  };
  auto stageB = [&](int t) {
    int k0 = t << 6, s = t % 3;
    #pragma unroll
    for (int i = 0; i < 2; ++i) {
      int c = i * 512 + tid;
      int row = c >> 3, ch = c & 7;
      gld16(Bt + (size_t)(c0 + row) * K + k0 + ((ch ^ (row & 7)) << 3),
            &Bs[s][(i * 512 + wv * 64) * 8]);
    }
  };

  fx4 acc[2][4][2] = {};
  bf16x8 a[4][2], b[2][2];

  auto ldA = [&](int s, int hh) {
    #pragma unroll
    for (int mf = 0; mf < 4; ++mf) {
      int lr = wm + mf * 16 + lrow;
      #pragma unroll
      for (int ks = 0; ks < 2; ++ks)
        a[mf][ks] = ld8(&As[s][hh][lr * 64 + ((((ks << 2) + lg) ^ (lr & 7)) << 3)]);
    }
  };
  auto ldB = [&](int s) {
    #pragma unroll
    for (int nf = 0; nf < 2; ++nf) {
      int lr = wn + nf * 16 + lrow;
      #pragma unroll
      for (int ks = 0; ks < 2; ++ks)
        b[nf][ks] = ld8(&Bs[s][lr * 64 + ((((ks << 2) + lg) ^ (lr & 7)) << 3)]);
    }
  };

  const int nt = K >> 6;
  stageA(0, 0); stageA(0, 1); stageB(0);
  stageA(1, 0); stageA(1, 1); stageB(1);

  for (int t = 0; t < nt; ++t) {
    const int s = t % 3;
    if (t + 1 < nt) wait_vmcnt<6>(); else wait_vmcnt<0>();
    barrier_pin();
    ldA(s, 0); ldB(s);
    if (t + 2 < nt) stageA(t + 2, 0);
    __builtin_amdgcn_s_setprio(1);
    #pragma unroll
    for (int ks = 0; ks < 2; ++ks)
      #pragma unroll
      for (int mf = 0; mf < 4; ++mf)
        #pragma unroll
        for (int nf = 0; nf < 2; ++nf)
          acc[0][mf][nf] = __builtin_amdgcn_mfma_f32_16x16x32_bf16(
              a[mf][ks], b[nf][ks], acc[0][mf][nf], 0, 0, 0);
    __builtin_amdgcn_s_setprio(0);
    barrier_pin();
    ldA(s, 1);
    if (t + 2 < nt) { stageA(t + 2, 1); stageB(t + 2); }
    __builtin_amdgcn_s_setprio(1);
    #pragma unroll
    for (int ks = 0; ks < 2; ++ks)
      #pragma unroll
      for (int mf = 0; mf < 4; ++mf)
        #pragma unroll
        for (int nf = 0; nf < 2; ++nf)
          acc[1][mf][nf] = __builtin_amdgcn_mfma_f32_16x16x32_bf16(
              a[mf][ks], b[nf][ks], acc[1][mf][nf], 0, 0, 0);
    __builtin_amdgcn_s_setprio(0);
    barrier_pin();
  }
  const int g4 = lg << 2;
  #pragma unroll
  for (int mh = 0; mh < 2; ++mh)
    #pragma unroll
    for (int mf = 0; mf < 4; ++mf)
      #pragma unroll
      for (int nf = 0; nf < 2; ++nf)
        #pragma unroll
        for (int j = 0; j < 4; ++j) {
          int row = r0 + mh * 128 + wm + mf * 16 + g4 + j;
          int col = c0 + wn + nf * 16 + lrow;
          Cp[(size_t)row * N + col] = acc[mh][mf][nf][j];
        }
}

// ---------------- RMSNorm + RoPE + KV scatter (bf16 xqkv input) --------------
__global__ __launch_bounds__(256) void nr_k(const short* __restrict__ xqkv,
    const float* __restrict__ qnw, const float* __restrict__ knw,
    const float* __restrict__ cosb, const float* __restrict__ sinb,
    const int* __restrict__ idx,
    short* __restrict__ qb, short* __restrict__ kbp, short* __restrict__ vbp,
    float* __restrict__ bufo) {
  int rid = blockIdx.x * 4 + (threadIdx.x >> 6);
  int l = threadIdx.x & 63;
  int type, t, h;
  if (rid < 65536)      { type = 0; t = rid >> 5; h = rid & 31; }
  else if (rid < 81920) { type = 1; int r = rid - 65536; t = r >> 3; h = r & 7; }
  else                  { type = 2; int r = rid - 81920; t = r >> 3; h = r & 7; }
  int s = t & 1023;
  const short* src = xqkv + (size_t)t * 6144 +
                     ((type == 0) ? h * 128 : (type == 1) ? 4096 + h * 128
                                                          : 5120 + h * 128);
  float e0 = b2f(src[l]), e1 = b2f(src[l + 64]);
  float out0, out1;
  if (type < 2) {
    float ss = e0 * e0 + e1 * e1;
    #pragma unroll
    for (int off = 1; off < 64; off <<= 1) ss += __shfl_xor(ss, off);
    float r = rsqrtf(ss * (1.0f / 128.0f) + 1e-6f);
    const float* nw = (type == 0) ? qnw : knw;
    float n0 = e0 * r * nw[l], n1 = e1 * r * nw[l + 64];
    float c0 = cosb[s * 128 + l], c1 = cosb[s * 128 + 64 + l];
    float s0 = sinb[s * 128 + l], s1 = sinb[s * 128 + 64 + l];
    out0 = n0 * c0 - n1 * s0;
    out1 = n1 * c1 + n0 * s1;
  } else { out0 = e0; out1 = e1; }
  if (type == 0) {
    short* d = qb + (size_t)t * 4096 + h * 128;
    d[l] = f2bf(out0); d[l + 64] = f2bf(out1);
  } else {
    int br = idx[t];
    float* bd = bufo + (size_t)br * 2048 + (type == 1 ? 0 : 1024) + h * 128;
    bd[l] = out0; bd[l + 64] = out1;
    short* d = (type == 1) ? kbp + (size_t)t * 1024 + h * 128
                           : vbp + (size_t)t * 1024 + h * 128;
    d[l] = f2bf(out0); d[l + 64] = f2bf(out1);
  }
}

// ---------------- causal GQA flash attention (8-wave, 128 q-rows/block) ------
#define KLD 136
#define PLD 72

__global__ __launch_bounds__(512) void attn_k(const short* __restrict__ qb,
    const short* __restrict__ kbp, const short* __restrict__ vbt,
    short* __restrict__ ob) {
  __shared__ short Ks[64 * KLD];
  __shared__ short Vs[128 * 64];
  __shared__ short Ps[8][16 * PLD];
  const int bid = blockIdx.x;
  const int p = 7 - (bid & 7), h = (bid >> 3) & 31, b = bid >> 8;
  const int kvh = h >> 2;
  const int tid = threadIdx.x, lane = tid & 63, w = tid >> 6;   // w 0..7
  const int lrow = lane & 15, lg = lane >> 4, lk = lg << 3;
  const int q0 = p << 7;
  const int ktmax = 2 * p + 1;
  const float SC2 = 0.088388347648318447f * 1.4426950408889634f; // scale*log2(e)

  bf16x8 qf[4];
  {
    const short* qp = qb + ((size_t)(b * 1024 + q0 + w * 16 + lrow) * 32 + h) * 128 + lk;
    #pragma unroll
    for (int kb4 = 0; kb4 < 4; ++kb4) qf[kb4] = ld8(qp + kb4 * 32);
  }

  const short* vt_base = vbt + (size_t)(b * 8 + kvh) * 128 * 1024;

  const int sd8 = (tid & 15) << 3;
  s16x8 kreg[2], vreg[2];
  auto ldkv = [&](int kv0) {
    #pragma unroll
    for (int it = 0; it < 2; ++it) {
      int r = (it << 5) + (tid >> 4);            // 0..63
      kreg[it] = *(const s16x8*)(kbp + ((size_t)(b * 1024 + kv0 + r) * 8 + kvh) * 128 + sd8);
      int d = (it << 6) + (tid >> 3);            // 0..127
      vreg[it] = *(const s16x8*)(vt_base + (size_t)d * 1024 + kv0 + ((tid & 7) << 3));
    }
  };
  auto wrkv = [&]() {
    #pragma unroll
    for (int it = 0; it < 2; ++it) {
      int r = (it << 5) + (tid >> 4);
      *(s16x8*)&Ks[r * KLD + sd8] = kreg[it];
      int d = (it << 6) + (tid >> 3);
      *(s16x8*)&Vs[d * 64 + (((tid & 7) ^ (d & 7)) << 3)] = vreg[it];
    }
  };

  float m[4], lsum[4];
  fx4 acc[8] = {};
  #pragma unroll
  for (int j = 0; j < 4; ++j) { m[j] = -3.0e38f; lsum[j] = 0.f; }

  ldkv(0);
  wrkv();
  __syncthreads();

  for (int kt = 0; kt <= ktmax; ++kt) {
    const int kv0 = kt << 6;
    if (kt < ktmax) ldkv((kt + 1) << 6);   // T14: issue next tile's loads early
    fx4 sf[4];
    #pragma unroll
    for (int nc = 0; nc < 4; ++nc) {
      fx4 z = {0.f, 0.f, 0.f, 0.f};
      sf[nc] = z;
      #pragma unroll
      for (int kb4 = 0; kb4 < 4; ++kb4) {
        bf16x8 kf = ld8(&Ks[(nc * 16 + lrow) * KLD + kb4 * 32 + lk]);
        sf[nc] = __builtin_amdgcn_mfma_f32_16x16x32_bf16(qf[kb4], kf, sf[nc], 0, 0, 0);
      }
    }
    if (kt >= ktmax - 1) {   // last two tiles straddle the causal diagonal
      #pragma unroll
      for (int nc = 0; nc < 4; ++nc)
        #pragma unroll
        for (int j = 0; j < 4; ++j) {
          int qr = q0 + w * 16 + (lg << 2) + j;
          int kc = kv0 + nc * 16 + lrow;
          if (kc > qr) sf[nc][j] = -3.0e38f;
        }
    }
    float pm[4];
    #pragma unroll
    for (int j = 0; j < 4; ++j) pm[j] = -3.0e38f;
    #pragma unroll
    for (int nc = 0; nc < 4; ++nc)
      #pragma unroll
      for (int j = 0; j < 4; ++j) pm[j] = fmaxf(pm[j], sf[nc][j]);
    #pragma unroll
    for (int j = 0; j < 4; ++j) {
      pm[j] = fmaxf(pm[j], __shfl_xor(pm[j], 1));
      pm[j] = fmaxf(pm[j], __shfl_xor(pm[j], 2));
      pm[j] = fmaxf(pm[j], __shfl_xor(pm[j], 4));
      pm[j] = fmaxf(pm[j], __shfl_xor(pm[j], 8));
    }
    float alpha[4], rs[4];
    #pragma unroll
    for (int j = 0; j < 4; ++j) {
      float mn = fmaxf(m[j], pm[j]);
      alpha[j] = exp2f((m[j] - mn) * SC2);
      m[j] = mn;
      rs[j] = 0.f;
    }
    #pragma unroll
    for (int nc = 0; nc < 4; ++nc)
      #pragma unroll
      for (int j = 0; j < 4; ++j) {
        float pv = exp2f((sf[nc][j] - m[j]) * SC2);
        rs[j] += pv;
        Ps[w][((lg << 2) + j) * PLD + nc * 16 + lrow] = f2bf(pv);
      }
    #pragma unroll
    for (int j = 0; j < 4; ++j) {
      rs[j] += __shfl_xor(rs[j], 1);
      rs[j] += __shfl_xor(rs[j], 2);
      rs[j] += __shfl_xor(rs[j], 4);
      rs[j] += __shfl_xor(rs[j], 8);
      lsum[j] = lsum[j] * alpha[j] + rs[j];
    }
    #pragma unroll
    for (int dg = 0; dg < 8; ++dg)
      #pragma unroll
      for (int j = 0; j < 4; ++j) acc[dg][j] *= alpha[j];
    #pragma unroll
    for (int kb2 = 0; kb2 < 2; ++kb2) {
      bf16x8 pf = ld8(&Ps[w][lrow * PLD + kb2 * 32 + lk]);
      #pragma unroll
      for (int dg = 0; dg < 8; ++dg) {
        int d = dg * 16 + lrow;
        int tch = (kb2 << 2) + lg;
        bf16x8 vf = ld8(&Vs[d * 64 + ((tch ^ (d & 7)) << 3)]);
        acc[dg] = __builtin_amdgcn_mfma_f32_16x16x32_bf16(pf, vf, acc[dg], 0, 0, 0);
      }
    }
    __syncthreads();
    if (kt < ktmax) {
      wrkv();
      __syncthreads();
    }
  }
  #pragma unroll
  for (int j = 0; j < 4; ++j) {
    float rl = 1.0f / lsum[j];
    int t = b * 1024 + q0 + w * 16 + (lg << 2) + j;
    short* op = ob + ((size_t)t * 32 + h) * 128;
    #pragma unroll
    for (int dg = 0; dg < 8; ++dg)
      op[dg * 16 + lrow] = f2bf(acc[dg][j] * rl);
  }
}

// ---------------- launcher ----------------
extern "C" void kernel_launch(void* const* d_in, const int* in_sizes, int n_in,
                              void* d_out, int out_size, void* d_ws, size_t ws_size,
                              hipStream_t stream) {
  (void)in_sizes; (void)n_in; (void)out_size; (void)ws_size;
  const float* x    = (const float*)d_in[0];
  const float* qw   = (const float*)d_in[1];
  const float* kvw  = (const float*)d_in[2];
  const float* ow   = (const float*)d_in[3];
  const float* qnw  = (const float*)d_in[4];
  const float* knw  = (const float*)d_in[5];
  const float* cosb = (const float*)d_in[6];
  const float* sinb = (const float*)d_in[7];
  const float* kvbf = (const float*)d_in[8];
  const int*   idx  = (const int*)d_in[9];

  float* outp = (float*)d_out;
  float* bufp = outp + (size_t)2048 * 4096;   // 16384 rows x 2048 f32 = 134 MB

  // workspace
  char* ws = (char*)d_ws;
  short* xqkv = (short*)ws;                                   // bf16 [2048][6144], 25 MB
  short* qb   = (short*)(ws + (size_t)2048 * 6144 * 4);       // 16.8 MB (offset keeps slack)
  short* kbp  = (short*)((char*)qb + (size_t)2048 * 4096 * 2); // 4.2 MB
  short* vbp  = (short*)((char*)kbp + (size_t)2048 * 1024 * 2);// 4.2 MB
  short* attnb = (short*)(ws + (size_t)2048 * 6144 * 2);      // after bf16 xqkv, 16.8 MB
  short* owt   = (short*)((char*)qb + (size_t)2048 * 4096 * 2 + (size_t)2048 * 2048 * 2 * 2); // after vbp
  short* vbt   = owt;   // vbt (4.2 MB) lives in owt region DURING attn

  // scratch inside the kv_buffer output region (dead until copied/scattered):
  //   rows 0..2047    -> xb   (bf16 [2048][4096], 16.8 MB; nr_k rewrites later)
  //   rows 2048..8191 -> wqkvt (bf16 [6144][4096], 50.3 MB; refilled by memcpy)
  //   rows 8192..16383-> fused-copy target during gemm8
  short* xb    = (short*)bufp;
  short* wqkvt = (short*)(bufp + (size_t)2048 * 2048);

  // 1) pre-convert x to bf16; transpose fused [qw|kvw] -> bf16 [6144][4096]
  cvt_k<<<dim3(4096), dim3(256), 0, stream>>>(x, xb);
  tr_k<<<dim3(64 * 64), dim3(256), 0, stream>>>(qw, wqkvt, 4096, 4096);
  tr_k<<<dim3(64 * 32), dim3(256), 0, stream>>>(kvw, wqkvt + (size_t)4096 * 4096, 4096, 2048);
  // 2) fused QKV projection (8-phase, bf16 out) + bulk kv-buffer copy of rows
  //    8192..16383 on the 64 idle CUs: grid 192 GEMM + 64 copy blocks
  {
    const fx4* csrc = (const fx4*)(kvbf + (size_t)8192 * 2048);
    fx4* cdst = (fx4*)(bufp + (size_t)8192 * 2048);
    size_t nvec = (size_t)8192 * 2048 / 4;   // 4.19M f32x4
    gemm8<1><<<dim3(256), dim3(512), 0, stream>>>(xb, wqkvt, (void*)xqkv, 6144, 4096,
                                                  csrc, cdst, 192, nvec);
  }
  // 3) residual kv buffer copy: rows 2048..8191 (kills wqkvt), then norm/rope/scatter
  hipMemcpyAsync(bufp + (size_t)2048 * 2048, kvbf + (size_t)2048 * 2048,
                 (size_t)6144 * 2048 * 4, hipMemcpyDeviceToDevice, stream);
  nr_k<<<dim3(98304 / 4), dim3(256), 0, stream>>>(xqkv, qnw, knw, cosb, sinb, idx,
                                                  qb, kbp, vbp, bufp);
  // 4) V transpose once (into owt region), then attention (8-wave blocks)
  vtr_k<<<dim3(512), dim3(256), 0, stream>>>(vbp, vbt);
  attn_k<<<dim3(2 * 32 * 8), dim3(512), 0, stream>>>(qb, kbp, vbt, attnb);
  // 5) O-weight transpose (overwrites vbt — attn done), then O-proj (4-phase)
  tr_k<<<dim3(64 * 64), dim3(256), 0, stream>>>(ow, owt, 4096, 4096);
  gemm4<<<dim3(8 * 32), dim3(512), 0, stream>>>(attnb, owt, outp, 4096, 4096);
}